// Round 2
// baseline (32101.169 us; speedup 1.0000x reference)
//
#include <hip/hip_runtime.h>

// 3-layer LSTM (H=64, B=256, S=4096, DIN=1) + linear head, fp32.
// One block per batch element; 512 threads = 8 waves (2/SIMD -> 256 VGPR cap).
// grp0 (tid<256): fuses layer0+layer1 per thread (shares the h0 LDS read).
// grp1 (tid>=256): layer2 + linear-head partial.
// Quad-gate layout: thread 4u+q owns gate row q*64+u -> i/f/g/o combine is
// 3 shfl_xor in a lane quad; ONE barrier/tick; h double-buffered in LDS.
// Skew: tick T computes l0@T, l1@T-1, l2@T-2, y-sum@T-3.

#define SQ 4096
#define HH 64
#define NB 256

__global__ __launch_bounds__(512, 2) void lstm3_fused(
    const float* __restrict__ x,
    const float* __restrict__ Wih0, const float* __restrict__ Whh0,
    const float* __restrict__ bih0, const float* __restrict__ bhh0,
    const float* __restrict__ Wih1, const float* __restrict__ Whh1,
    const float* __restrict__ bih1, const float* __restrict__ bhh1,
    const float* __restrict__ Wih2, const float* __restrict__ Whh2,
    const float* __restrict__ bih2, const float* __restrict__ bhh2,
    const float* __restrict__ Wlin, const float* __restrict__ blin,
    float* __restrict__ out)
{
    const int b   = blockIdx.x;
    const int tid = threadIdx.x;
    const int grp = tid >> 8;          // 0: layers 0+1, 1: layer 2
    const int k   = tid & 255;
    const int u   = k >> 2;            // hidden unit
    const int q   = k & 3;             // gate (0=i,1=f,2=g,3=o)
    const int row = q * HH + u;        // gate row in [0,256)

    __shared__ __align__(16) float xrow[SQ];
    __shared__ __align__(16) float hb[2][3][HH];   // [buf][layer][unit]
    __shared__ float ybuf[2][4];

    for (int i = tid; i < SQ; i += 512) xrow[i] = x[b * SQ + i];
    if (tid < HH) {
        hb[0][0][tid] = 0.f; hb[0][1][tid] = 0.f; hb[0][2][tid] = 0.f;
        hb[1][0][tid] = 0.f; hb[1][1][tid] = 0.f; hb[1][2][tid] = 0.f;
    }
    if (tid < 8) ybuf[tid >> 2][tid & 3] = 0.f;

    // ---- weights in registers ----
    float4 wA[16], wB[16], wC[16];     // grp0: Whh0row / Wih1row / Whh1row
                                       // grp1:   --    / Wih2row / Whh2row
    float wih0 = 0.f, biasA = 0.f, biasB = 0.f, wlin_u = 0.f;
    const float blin_v = blin[0];

    if (grp == 0) {
        biasA = bih0[row] + bhh0[row];
        biasB = bih1[row] + bhh1[row];
        wih0  = Wih0[row];
        const float4* pa = (const float4*)(Whh0 + row * HH);
        const float4* pb = (const float4*)(Wih1 + row * HH);
        const float4* pc = (const float4*)(Whh1 + row * HH);
#pragma unroll
        for (int j = 0; j < 16; ++j) { wA[j] = pa[j]; wB[j] = pb[j]; wC[j] = pc[j]; }
    } else {
        biasB = bih2[row] + bhh2[row];
        const float4* pb = (const float4*)(Wih2 + row * HH);
        const float4* pc = (const float4*)(Whh2 + row * HH);
#pragma unroll
        for (int j = 0; j < 16; ++j) {
            wA[j] = make_float4(0.f, 0.f, 0.f, 0.f);
            wB[j] = pb[j]; wC[j] = pc[j];
        }
        if (q == 0) wlin_u = Wlin[u];
    }

    // gate activation: q==2 -> tanh = 2*sigm(2x)-1, else sigm(x)
    const float s1 = (q == 2) ? 2.f : 1.f;
    const float o1 = (q == 2) ? 1.f : 0.f;

    float cA = 0.f, cB = 0.f;          // cell states (held by q==0 leaders)

    __syncthreads();

    for (int T = 0; T < SQ + 3; ++T) {
        const int rd = T & 1;
        const int wr = rd ^ 1;
        const float4* h0p = (const float4*)&hb[rd][0][0];
        const float4* h1p = (const float4*)&hb[rd][1][0];
        const float4* h2p = (const float4*)&hb[rd][2][0];

        if (grp == 0) {
            // layer0 row: wih0*x_T + Whh0row . h0   (step T)
            // layer1 row: Wih1row . h0 + Whh1row . h1   (step T-1)
            const int xi = (T < SQ) ? T : 0;
            float sA0 = biasA + wih0 * xrow[xi], sA1 = 0.f;
            float sB0 = biasB, sB1 = 0.f;
#pragma unroll
            for (int j = 0; j < 16; ++j) {
                float4 v = h0p[j];
                sA0 += wA[j].x * v.x + wA[j].y * v.y;
                sA1 += wA[j].z * v.z + wA[j].w * v.w;
                sB0 += wB[j].x * v.x + wB[j].y * v.y;
                sB1 += wB[j].z * v.z + wB[j].w * v.w;
            }
#pragma unroll
            for (int j = 0; j < 16; ++j) {
                float4 v = h1p[j];
                sB0 += wC[j].x * v.x + wC[j].y * v.y;
                sB1 += wC[j].z * v.z + wC[j].w * v.w;
            }
            const float gA = sA0 + sA1;
            const float gB = sB0 + sB1;
            float tA = 1.f / (1.f + __expf(-s1 * gA));
            float tB = 1.f / (1.f + __expf(-s1 * gB));
            const float actA = s1 * tA - o1;
            const float actB = s1 * tB - o1;
            const float vA1 = __shfl_xor(actA, 1), vA2 = __shfl_xor(actA, 2), vA3 = __shfl_xor(actA, 3);
            const float vB1 = __shfl_xor(actB, 1), vB2 = __shfl_xor(actB, 2), vB3 = __shfl_xor(actB, 3);
            if (q == 0) {
                if (T < SQ) {                       // layer0 step T
                    cA = vA1 * cA + actA * vA2;
                    float tc = fminf(fmaxf(cA, -15.f), 15.f);
                    float e  = __expf(-2.f * tc);
                    float h  = vA3 * ((1.f - e) / (1.f + e));
                    hb[wr][0][u] = h;
                    if (T == SQ - 1) {
                        out[NB * SQ + 0 * NB * HH + b * HH + u] = h;
                        out[NB * SQ + 3 * NB * HH + 0 * NB * HH + b * HH + u] = cA;
                    }
                }
                const int s1step = T - 1;
                if (s1step >= 0 && s1step < SQ) {   // layer1 step T-1
                    cB = vB1 * cB + actB * vB2;
                    float tc = fminf(fmaxf(cB, -15.f), 15.f);
                    float e  = __expf(-2.f * tc);
                    float h  = vB3 * ((1.f - e) / (1.f + e));
                    hb[wr][1][u] = h;
                    if (s1step == SQ - 1) {
                        out[NB * SQ + 1 * NB * HH + b * HH + u] = h;
                        out[NB * SQ + 3 * NB * HH + 1 * NB * HH + b * HH + u] = cB;
                    }
                }
            }
            // y reader: sum previous tick's wave partials (step T-3)
            if (k == 3) {
                const int sy = T - 3;
                if (sy >= 0 && sy < SQ) {
                    const float* yb = ybuf[(T - 1) & 1];
                    out[b * SQ + sy] = (yb[0] + yb[1]) + (yb[2] + yb[3]) + blin_v;
                }
            }
        } else {
            // layer2 row: Wih2row . h1 + Whh2row . h2   (step T-2)
            float sB0 = biasB, sB1 = 0.f, sC0 = 0.f, sC1 = 0.f;
#pragma unroll
            for (int j = 0; j < 16; ++j) {
                float4 v = h1p[j];
                sB0 += wB[j].x * v.x + wB[j].y * v.y;
                sB1 += wB[j].z * v.z + wB[j].w * v.w;
            }
#pragma unroll
            for (int j = 0; j < 16; ++j) {
                float4 v = h2p[j];
                sC0 += wC[j].x * v.x + wC[j].y * v.y;
                sC1 += wC[j].z * v.z + wC[j].w * v.w;
            }
            const float gB = (sB0 + sB1) + (sC0 + sC1);
            float tB = 1.f / (1.f + __expf(-s1 * gB));
            const float actB = s1 * tB - o1;
            const float vB1 = __shfl_xor(actB, 1), vB2 = __shfl_xor(actB, 2), vB3 = __shfl_xor(actB, 3);
            float yv = 0.f;
            const int s2step = T - 2;
            if (q == 0 && s2step >= 0 && s2step < SQ) {
                cB = vB1 * cB + actB * vB2;
                float tc = fminf(fmaxf(cB, -15.f), 15.f);
                float e  = __expf(-2.f * tc);
                float h  = vB3 * ((1.f - e) / (1.f + e));
                hb[wr][2][u] = h;
                yv = wlin_u * h;
                if (s2step == SQ - 1) {
                    out[NB * SQ + 2 * NB * HH + b * HH + u] = h;
                    out[NB * SQ + 3 * NB * HH + 2 * NB * HH + b * HH + u] = cB;
                }
            }
#pragma unroll
            for (int m = 1; m < 64; m <<= 1) yv += __shfl_xor(yv, m, 64);
            if ((k & 63) == 0) ybuf[T & 1][(tid >> 6) & 3] = yv;
        }
        __syncthreads();
    }
}

extern "C" void kernel_launch(void* const* d_in, const int* in_sizes, int n_in,
                              void* d_out, int out_size, void* d_ws, size_t ws_size,
                              hipStream_t stream) {
    const float* x    = (const float*)d_in[0];
    const float* Wih0 = (const float*)d_in[1];
    const float* Whh0 = (const float*)d_in[2];
    const float* bih0 = (const float*)d_in[3];
    const float* bhh0 = (const float*)d_in[4];
    const float* Wih1 = (const float*)d_in[5];
    const float* Whh1 = (const float*)d_in[6];
    const float* bih1 = (const float*)d_in[7];
    const float* bhh1 = (const float*)d_in[8];
    const float* Wih2 = (const float*)d_in[9];
    const float* Whh2 = (const float*)d_in[10];
    const float* bih2 = (const float*)d_in[11];
    const float* bhh2 = (const float*)d_in[12];
    const float* Wlin = (const float*)d_in[13];
    const float* blin = (const float*)d_in[14];
    float* out = (float*)d_out;

    lstm3_fused<<<NB, 512, 0, stream>>>(x, Wih0, Whh0, bih0, bhh0,
                                        Wih1, Whh1, bih1, bhh1,
                                        Wih2, Whh2, bih2, bhh2,
                                        Wlin, blin, out);
}

// Round 3
// 4625.079 us; speedup vs baseline: 6.9407x; 6.9407x over previous
//
#include <hip/hip_runtime.h>

// 3-layer LSTM (H=64, B=256, S=4096, DIN=1) + linear head.
// One block per batch element, 768 threads = 3 groups of 256, group l owns
// layer l with skew (tick T: l0@T, l1@T-1, l2@T-2, y-write@T-3).
// Weights held as fp16 in ext-vector SSA values (NOT arrays -> guaranteed
// VGPRs, no scratch). Dot products via v_dot2_f32_f16 (fp32 accumulate).
// h exchanged through LDS as fp16, double-buffered; ONE barrier per tick.
// Quad-gate layout: thread 4u+q owns gate row q*64+u; i/f/g/o combine is
// 3 shfl_xor within the lane quad.

#define SQ 4096
#define HH 64
#define NB 256

typedef _Float16 h2  __attribute__((ext_vector_type(2)));
typedef _Float16 h32 __attribute__((ext_vector_type(32)));

__device__ __forceinline__ void load_row(const float* __restrict__ p, h32& lo, h32& hi) {
#pragma unroll
    for (int j = 0; j < 32; ++j) lo[j] = (_Float16)p[j];
#pragma unroll
    for (int j = 0; j < 32; ++j) hi[j] = (_Float16)p[32 + j];
}

__device__ __forceinline__ float dot64(h32 lo, h32 hi, const h2* __restrict__ hp, float init) {
    float a0 = init, a1 = 0.f, a2 = 0.f, a3 = 0.f;
#pragma unroll
    for (int p = 0; p < 4; ++p) {
        h2 w0 = {lo[8*p+0], lo[8*p+1]};
        h2 w1 = {lo[8*p+2], lo[8*p+3]};
        h2 w2 = {lo[8*p+4], lo[8*p+5]};
        h2 w3 = {lo[8*p+6], lo[8*p+7]};
        a0 = __builtin_amdgcn_fdot2(w0, hp[4*p+0], a0, false);
        a1 = __builtin_amdgcn_fdot2(w1, hp[4*p+1], a1, false);
        a2 = __builtin_amdgcn_fdot2(w2, hp[4*p+2], a2, false);
        a3 = __builtin_amdgcn_fdot2(w3, hp[4*p+3], a3, false);
    }
#pragma unroll
    for (int p = 0; p < 4; ++p) {
        h2 w0 = {hi[8*p+0], hi[8*p+1]};
        h2 w1 = {hi[8*p+2], hi[8*p+3]};
        h2 w2 = {hi[8*p+4], hi[8*p+5]};
        h2 w3 = {hi[8*p+6], hi[8*p+7]};
        a0 = __builtin_amdgcn_fdot2(w0, hp[16+4*p+0], a0, false);
        a1 = __builtin_amdgcn_fdot2(w1, hp[16+4*p+1], a1, false);
        a2 = __builtin_amdgcn_fdot2(w2, hp[16+4*p+2], a2, false);
        a3 = __builtin_amdgcn_fdot2(w3, hp[16+4*p+3], a3, false);
    }
    return (a0 + a1) + (a2 + a3);
}

__global__ __launch_bounds__(768, 2) void lstm3_fused(
    const float* __restrict__ x,
    const float* __restrict__ Wih0, const float* __restrict__ Whh0,
    const float* __restrict__ bih0, const float* __restrict__ bhh0,
    const float* __restrict__ Wih1, const float* __restrict__ Whh1,
    const float* __restrict__ bih1, const float* __restrict__ bhh1,
    const float* __restrict__ Wih2, const float* __restrict__ Whh2,
    const float* __restrict__ bih2, const float* __restrict__ bhh2,
    const float* __restrict__ Wlin, const float* __restrict__ blin,
    float* __restrict__ out)
{
    const int b   = blockIdx.x;
    const int tid = threadIdx.x;
    const int grp = tid >> 8;          // layer 0,1,2
    const int k   = tid & 255;
    const int u   = k >> 2;            // hidden unit
    const int q   = k & 3;             // gate (0=i,1=f,2=g,3=o)
    const int row = q * HH + u;

    __shared__ __align__(16) float xrow[SQ];
    __shared__ __align__(16) h2 hbf[2][3][32];   // [buf][layer][pair]
    __shared__ float ybuf[2][4];

    for (int i = tid; i < SQ; i += 768) xrow[i] = x[b * SQ + i];
    if (tid < 192) ((int*)hbf)[tid] = 0;         // zero both h buffers
    if (tid < 8) ybuf[tid >> 2][tid & 3] = 0.f;

    // ---- weights (SSA fp16 vectors; wb only used by grp 1/2) ----
    h32 wa_lo = {}, wa_hi = {}, wb_lo = {}, wb_hi = {};
    float bias = 0.f, wih0 = 0.f, wlin_u = 0.f;
    const float blin_v = blin[0];

    if (grp == 0) {
        bias = bih0[row] + bhh0[row];
        wih0 = Wih0[row];
        load_row(Whh0 + row * HH, wa_lo, wa_hi);
    } else if (grp == 1) {
        bias = bih1[row] + bhh1[row];
        load_row(Wih1 + row * HH, wa_lo, wa_hi);
        load_row(Whh1 + row * HH, wb_lo, wb_hi);
    } else {
        bias = bih2[row] + bhh2[row];
        load_row(Wih2 + row * HH, wa_lo, wa_hi);
        load_row(Whh2 + row * HH, wb_lo, wb_hi);
        if (q == 0) wlin_u = Wlin[u];
    }

    const float s1 = (q == 2) ? 2.f : 1.f;   // tanh = 2*sigm(2x)-1 for gate g
    const float o1 = (q == 2) ? 1.f : 0.f;
    float cc = 0.f;                          // cell state (leaders q==0)

    __syncthreads();

    for (int T = 0; T < SQ + 3; ++T) {
        const int rd = T & 1;
        const int wr = rd ^ 1;

        float g;
        if (grp == 0) {
            g = bias + wih0 * xrow[(T < SQ) ? T : 0];
            g = dot64(wa_lo, wa_hi, &hbf[rd][0][0], g);
        } else if (grp == 1) {
            g = dot64(wa_lo, wa_hi, &hbf[rd][0][0], bias);
            g = dot64(wb_lo, wb_hi, &hbf[rd][1][0], g);
        } else {
            g = dot64(wa_lo, wa_hi, &hbf[rd][1][0], bias);
            g = dot64(wb_lo, wb_hi, &hbf[rd][2][0], g);
        }

        float t = 1.f / (1.f + __expf(-s1 * g));
        const float act = s1 * t - o1;       // sigm for i,f,o; tanh for g
        const float v1 = __shfl_xor(act, 1);
        const float v2 = __shfl_xor(act, 2);
        const float v3 = __shfl_xor(act, 3);

        const int step = T - grp;
        float yv = 0.f;
        if (q == 0 && step >= 0 && step < SQ) {
            cc = v1 * cc + act * v2;         // sigm(f)*c + sigm(i)*tanh(g)
            float tc = fminf(fmaxf(cc, -15.f), 15.f);
            float e  = __expf(-2.f * tc);
            float h  = v3 * ((1.f - e) / (1.f + e));   // sigm(o)*tanh(c)
            ((_Float16*)&hbf[wr][grp][0])[u] = (_Float16)h;
            if (grp == 2) yv = wlin_u * h;
            if (step == SQ - 1) {
                out[NB * SQ + grp * NB * HH + b * HH + u] = h;
                out[NB * SQ + 3 * NB * HH + grp * NB * HH + b * HH + u] = cc;
            }
        }
        if (grp == 2) {
#pragma unroll
            for (int m = 1; m < 64; m <<= 1) yv += __shfl_xor(yv, m, 64);
            if ((k & 63) == 0) ybuf[T & 1][k >> 6] = yv;
        }
        if (grp == 0 && k == 255) {
            const int sy = T - 3;
            if (sy >= 0 && sy < SQ) {
                const float* yb = ybuf[(T - 1) & 1];
                out[b * SQ + sy] = (yb[0] + yb[1]) + (yb[2] + yb[3]) + blin_v;
            }
        }
        __syncthreads();
    }
}

extern "C" void kernel_launch(void* const* d_in, const int* in_sizes, int n_in,
                              void* d_out, int out_size, void* d_ws, size_t ws_size,
                              hipStream_t stream) {
    const float* x    = (const float*)d_in[0];
    const float* Wih0 = (const float*)d_in[1];
    const float* Whh0 = (const float*)d_in[2];
    const float* bih0 = (const float*)d_in[3];
    const float* bhh0 = (const float*)d_in[4];
    const float* Wih1 = (const float*)d_in[5];
    const float* Whh1 = (const float*)d_in[6];
    const float* bih1 = (const float*)d_in[7];
    const float* bhh1 = (const float*)d_in[8];
    const float* Wih2 = (const float*)d_in[9];
    const float* Whh2 = (const float*)d_in[10];
    const float* bih2 = (const float*)d_in[11];
    const float* bhh2 = (const float*)d_in[12];
    const float* Wlin = (const float*)d_in[13];
    const float* blin = (const float*)d_in[14];
    float* out = (float*)d_out;

    lstm3_fused<<<NB, 768, 0, stream>>>(x, Wih0, Whh0, bih0, bhh0,
                                        Wih1, Whh1, bih1, bhh1,
                                        Wih2, Whh2, bih2, bhh2,
                                        Wlin, blin, out);
}

// Round 5
// 4146.731 us; speedup vs baseline: 7.7413x; 1.1154x over previous
//
#include <hip/hip_runtime.h>

// 3-layer LSTM (H=64, B=256, S=4096, DIN=1) + linear head.
// One block per batch element, 768 threads = 3 groups of 256 (group = layer),
// skewed pipeline (tick T: l0@T, l1@T-1, l2@T-2, y-write@T-3).
// Col-split matvec: thread (u,qt) owns ALL 4 gate rows of unit u over col
// quarter qt -> reads only 16 h values (2 x ds_read_b128) per matvec.
// Quad transpose-reduce (3 shfl_xor) -> lane 4u+qt holds gate qt of unit u.
// Weights fp16 in SSA ext-vectors (no arrays -> no scratch), fdot2 fp32 acc.
// R5 fix: zero ALL 192 ints of hbf (R4 zeroed 96 -> garbage h1[-1] polluted
// early y values, absmax 2.4e-2).

#define SQ 4096
#define HH 64
#define NB 256

typedef _Float16 h2   __attribute__((ext_vector_type(2)));
typedef _Float16 hv8  __attribute__((ext_vector_type(8)));
typedef _Float16 hv16 __attribute__((ext_vector_type(16)));

__device__ __forceinline__ hv16 load_seg(const float* __restrict__ p) {
    hv16 r;
#pragma unroll
    for (int j = 0; j < 16; ++j) r[j] = (_Float16)p[j];
    return r;
}

// dot of 16 fp16 weights with 16 fp16 h values (two hv8 fragments)
__device__ __forceinline__ float dotseg(hv16 w, hv8 ha, hv8 hb, float acc) {
#pragma unroll
    for (int j = 0; j < 4; ++j) {
        h2 wp = {w[2*j], w[2*j+1]};
        h2 hp = {ha[2*j], ha[2*j+1]};
        acc = __builtin_amdgcn_fdot2(wp, hp, acc, false);
    }
#pragma unroll
    for (int j = 0; j < 4; ++j) {
        h2 wp = {w[8+2*j], w[8+2*j+1]};
        h2 hp = {hb[2*j], hb[2*j+1]};
        acc = __builtin_amdgcn_fdot2(wp, hp, acc, false);
    }
    return acc;
}

__global__ __launch_bounds__(768, 3) void lstm3_fused(
    const float* __restrict__ x,
    const float* __restrict__ Wih0, const float* __restrict__ Whh0,
    const float* __restrict__ bih0, const float* __restrict__ bhh0,
    const float* __restrict__ Wih1, const float* __restrict__ Whh1,
    const float* __restrict__ bih1, const float* __restrict__ bhh1,
    const float* __restrict__ Wih2, const float* __restrict__ Whh2,
    const float* __restrict__ bih2, const float* __restrict__ bhh2,
    const float* __restrict__ Wlin, const float* __restrict__ blin,
    float* __restrict__ out)
{
    const int b   = blockIdx.x;
    const int tid = threadIdx.x;
    const int grp = tid >> 8;          // layer 0,1,2
    const int k   = tid & 255;
    const int u   = k >> 2;            // hidden unit
    const int qt  = k & 3;             // col quarter AND final gate index
    const int row = qt * HH + u;       // this thread's final gate row

    __shared__ __align__(16) float xrow[SQ];
    __shared__ __align__(16) _Float16 hbf[2][3][HH];   // [buf][layer][unit]
    __shared__ float ybuf[2][4];

    for (int i = tid; i < SQ; i += 768) xrow[i] = x[b * SQ + i];
    if (tid < 192) ((int*)hbf)[tid] = 0;               // zero BOTH h buffers (192 ints)
    if (tid < 8) ybuf[tid >> 2][tid & 3] = 0.f;

    // ---- weights: 4 gate-segments per matvec, fp16 SSA vectors ----
    const float* WA = (grp == 0) ? Whh0 : (grp == 1) ? Wih1 : Wih2;
    const float* WB = (grp == 2) ? Whh2 : Whh1;        // unused by grp0
    hv16 wA0 = load_seg(WA + (0 * HH + u) * HH + 16 * qt);
    hv16 wA1 = load_seg(WA + (1 * HH + u) * HH + 16 * qt);
    hv16 wA2 = load_seg(WA + (2 * HH + u) * HH + 16 * qt);
    hv16 wA3 = load_seg(WA + (3 * HH + u) * HH + 16 * qt);
    hv16 wB0 = {}, wB1 = {}, wB2 = {}, wB3 = {};
    if (grp != 0) {
        wB0 = load_seg(WB + (0 * HH + u) * HH + 16 * qt);
        wB1 = load_seg(WB + (1 * HH + u) * HH + 16 * qt);
        wB2 = load_seg(WB + (2 * HH + u) * HH + 16 * qt);
        wB3 = load_seg(WB + (3 * HH + u) * HH + 16 * qt);
    }

    float bias = 0.f, wih0 = 0.f, wlin_u = 0.f;
    if (grp == 0) { bias = bih0[row] + bhh0[row]; wih0 = Wih0[row]; }
    else if (grp == 1) bias = bih1[row] + bhh1[row];
    else { bias = bih2[row] + bhh2[row]; if (qt == 0) wlin_u = Wlin[u]; }
    const float blin_v = blin[0];

    const int la = (grp == 2) ? 1 : 0;     // A-matvec h source layer
    const int lb = grp;                    // B-matvec h source layer (own)
    const int b0c = qt & 1, b1c = (qt >> 1) & 1;
    const float s1 = (qt == 2) ? 2.f : 1.f;   // tanh = 2*sigm(2x)-1 for gate g
    const float o1 = (qt == 2) ? 1.f : 0.f;
    float cc = 0.f;                        // cell state (leaders qt==0)

    __syncthreads();

    auto tick = [&](int T) {
        const int rd = T & 1;
        const int wr = rd ^ 1;

        // ---- partial dot: 4 gate rows x 16 cols ----
        const hv8* hp = (const hv8*)&hbf[rd][la][0];
        hv8 a0 = hp[2 * qt], a1 = hp[2 * qt + 1];
        float p0 = dotseg(wA0, a0, a1, 0.f);
        float p1 = dotseg(wA1, a0, a1, 0.f);
        float p2 = dotseg(wA2, a0, a1, 0.f);
        float p3 = dotseg(wA3, a0, a1, 0.f);
        if (grp != 0) {
            const hv8* hq = (const hv8*)&hbf[rd][lb][0];
            hv8 c0 = hq[2 * qt], c1 = hq[2 * qt + 1];
            p0 = dotseg(wB0, c0, c1, p0);
            p1 = dotseg(wB1, c0, c1, p1);
            p2 = dotseg(wB2, c0, c1, p2);
            p3 = dotseg(wB3, c0, c1, p3);
        }

        // ---- quad transpose-reduce: lane qt ends with full sum of gate qt ----
        float k0 = (b0c ? p1 : p0) + __shfl_xor(b0c ? p0 : p1, 1);
        float k1 = (b0c ? p3 : p2) + __shfl_xor(b0c ? p2 : p3, 1);
        float g  = (b1c ? k1 : k0) + __shfl_xor(b1c ? k0 : k1, 2);
        g += bias;
        if (grp == 0) g += wih0 * xrow[(T < SQ) ? T : 0];

        // ---- activation + quad combine ----
        float t = 1.f / (1.f + __expf(-s1 * g));
        const float act = s1 * t - o1;     // sigm for i,f,o; tanh for g
        const float v1 = __shfl_xor(act, 1);
        const float v2 = __shfl_xor(act, 2);
        const float v3 = __shfl_xor(act, 3);

        const int step = T - grp;
        float yv = 0.f;
        if (qt == 0 && step >= 0 && step < SQ) {
            cc = v1 * cc + act * v2;       // sigm(f)*c + sigm(i)*tanh(g)
            float tc = fminf(fmaxf(cc, -15.f), 15.f);
            float e  = __expf(-2.f * tc);
            float h  = v3 * ((1.f - e) / (1.f + e));   // sigm(o)*tanh(c)
            hbf[wr][grp][u] = (_Float16)h;
            if (grp == 2) yv = wlin_u * h;
            if (step == SQ - 1) {
                out[NB * SQ + grp * NB * HH + b * HH + u] = h;
                out[NB * SQ + 3 * NB * HH + grp * NB * HH + b * HH + u] = cc;
            }
        }
        if (grp == 2) {
#pragma unroll
            for (int m = 1; m < 64; m <<= 1) yv += __shfl_xor(yv, m, 64);
            if ((k & 63) == 0) ybuf[T & 1][k >> 6] = yv;
        }
        if (grp == 0 && k == 255) {
            const int sy = T - 3;
            if (sy >= 0 && sy < SQ) {
                const float* yb = ybuf[(T - 1) & 1];
                out[b * SQ + sy] = (yb[0] + yb[1]) + (yb[2] + yb[3]) + blin_v;
            }
        }
        __syncthreads();
    };

    for (int T = 0; T < SQ + 4; T += 2) {  // bodies T=0..4099, 2x unrolled
        tick(T);
        tick(T + 1);
    }
}

extern "C" void kernel_launch(void* const* d_in, const int* in_sizes, int n_in,
                              void* d_out, int out_size, void* d_ws, size_t ws_size,
                              hipStream_t stream) {
    const float* x    = (const float*)d_in[0];
    const float* Wih0 = (const float*)d_in[1];
    const float* Whh0 = (const float*)d_in[2];
    const float* bih0 = (const float*)d_in[3];
    const float* bhh0 = (const float*)d_in[4];
    const float* Wih1 = (const float*)d_in[5];
    const float* Whh1 = (const float*)d_in[6];
    const float* bih1 = (const float*)d_in[7];
    const float* bhh1 = (const float*)d_in[8];
    const float* Wih2 = (const float*)d_in[9];
    const float* Whh2 = (const float*)d_in[10];
    const float* bih2 = (const float*)d_in[11];
    const float* bhh2 = (const float*)d_in[12];
    const float* Wlin = (const float*)d_in[13];
    const float* blin = (const float*)d_in[14];
    float* out = (float*)d_out;

    lstm3_fused<<<NB, 768, 0, stream>>>(x, Wih0, Whh0, bih0, bhh0,
                                        Wih1, Whh1, bih1, bhh1,
                                        Wih2, Whh2, bih2, bhh2,
                                        Wlin, blin, out);
}

// Round 6
// 3416.812 us; speedup vs baseline: 9.3951x; 1.2136x over previous
//
#include <hip/hip_runtime.h>
#include <stdint.h>

// 3-layer LSTM (H=64, B=256, S=4096, DIN=1) + linear head.
// One block/batch element; 768 thr = 3 groups of 256 (group = layer), skewed
// pipeline (tick T: l0@T, l1@T-1, l2@T-2, y@T-3). Col-split matvec: thread
// (u,qt) does all 4 gate rows of unit u over col quarter qt (2 ds_read_b128).
// R6: pure-32-bit codegen. Weights = uint32 ext-vectors (fp16 pairs), h read
// as uint4, bit_cast to h2 at fdot2 -> dotseg is exactly 8 v_dot2_f32_f16.
// Quad shuffles via DPP quad_perm (VALU) instead of ds_bpermute. Literal
// rd/wr buffer indices -> zero per-tick LDS address math.

#define SQ 4096
#define HH 64
#define NB 256

typedef _Float16 h2  __attribute__((ext_vector_type(2)));
typedef uint32_t uv8 __attribute__((ext_vector_type(8)));

__device__ __forceinline__ h2 bch2(uint32_t u) { return __builtin_bit_cast(h2, u); }

template<int CTRL>
__device__ __forceinline__ float fdpp(float v) {
    return __builtin_bit_cast(float,
        __builtin_amdgcn_mov_dpp(__builtin_bit_cast(int, v), CTRL, 0xF, 0xF, true));
}
// quad_perm encodings: xor1=(1,0,3,2), xor2=(2,3,0,1), xor3=(3,2,1,0)
#define DPP_XOR1 0xB1
#define DPP_XOR2 0x4E
#define DPP_XOR3 0x1B
#define DPP_ROR4 0x124
#define DPP_ROR8 0x128

__device__ __forceinline__ uv8 load_seg(const float* __restrict__ p) {
    uv8 r;
#pragma unroll
    for (int j = 0; j < 8; ++j) {
        h2 t; t[0] = (_Float16)p[2 * j]; t[1] = (_Float16)p[2 * j + 1];
        r[j] = __builtin_bit_cast(uint32_t, t);
    }
    return r;
}

// 16 fp16 weights (8 packed u32) . 16 fp16 h (two uint4) -> fp32 acc
__device__ __forceinline__ float dotseg(uv8 w, uint4 a, uint4 b, float acc) {
    acc = __builtin_amdgcn_fdot2(bch2(w[0]), bch2(a.x), acc, false);
    acc = __builtin_amdgcn_fdot2(bch2(w[1]), bch2(a.y), acc, false);
    acc = __builtin_amdgcn_fdot2(bch2(w[2]), bch2(a.z), acc, false);
    acc = __builtin_amdgcn_fdot2(bch2(w[3]), bch2(a.w), acc, false);
    acc = __builtin_amdgcn_fdot2(bch2(w[4]), bch2(b.x), acc, false);
    acc = __builtin_amdgcn_fdot2(bch2(w[5]), bch2(b.y), acc, false);
    acc = __builtin_amdgcn_fdot2(bch2(w[6]), bch2(b.z), acc, false);
    acc = __builtin_amdgcn_fdot2(bch2(w[7]), bch2(b.w), acc, false);
    return acc;
}

__global__ __launch_bounds__(768, 3) void lstm3_fused(
    const float* __restrict__ x,
    const float* __restrict__ Wih0, const float* __restrict__ Whh0,
    const float* __restrict__ bih0, const float* __restrict__ bhh0,
    const float* __restrict__ Wih1, const float* __restrict__ Whh1,
    const float* __restrict__ bih1, const float* __restrict__ bhh1,
    const float* __restrict__ Wih2, const float* __restrict__ Whh2,
    const float* __restrict__ bih2, const float* __restrict__ bhh2,
    const float* __restrict__ Wlin, const float* __restrict__ blin,
    float* __restrict__ out)
{
    const int b   = blockIdx.x;
    const int tid = threadIdx.x;
    const int grp = tid >> 8;          // layer 0,1,2
    const int k   = tid & 255;
    const int u   = k >> 2;            // hidden unit
    const int qt  = k & 3;             // col quarter AND final gate index
    const int row = qt * HH + u;       // this thread's final gate row

    __shared__ __align__(16) float xrow[SQ];
    __shared__ __align__(16) uint4 hbf[2][3][8];   // [buf][layer][8x uint4 = 64 fp16]
    __shared__ __align__(16) float ybuf[2][16];    // per-row head partials

    for (int i = tid; i < SQ; i += 768) xrow[i] = x[b * SQ + i];
    if (tid < 48) ((uint4*)hbf)[tid] = make_uint4(0, 0, 0, 0);
    if (tid < 32) ((float*)ybuf)[tid] = 0.f;

    // ---- weights: 4 gate-row segments per matvec, packed fp16 in u32 SSA ----
    const float* WA = (grp == 0) ? Whh0 : (grp == 1) ? Wih1 : Wih2;
    const float* WB = (grp == 2) ? Whh2 : Whh1;        // unused by grp0
    uv8 wA0 = load_seg(WA + (0 * HH + u) * HH + 16 * qt);
    uv8 wA1 = load_seg(WA + (1 * HH + u) * HH + 16 * qt);
    uv8 wA2 = load_seg(WA + (2 * HH + u) * HH + 16 * qt);
    uv8 wA3 = load_seg(WA + (3 * HH + u) * HH + 16 * qt);
    uv8 wB0 = {}, wB1 = {}, wB2 = {}, wB3 = {};
    if (grp != 0) {
        wB0 = load_seg(WB + (0 * HH + u) * HH + 16 * qt);
        wB1 = load_seg(WB + (1 * HH + u) * HH + 16 * qt);
        wB2 = load_seg(WB + (2 * HH + u) * HH + 16 * qt);
        wB3 = load_seg(WB + (3 * HH + u) * HH + 16 * qt);
    }

    float bias = 0.f, wih0 = 0.f, wlin_u = 0.f;
    if (grp == 0) { bias = bih0[row] + bhh0[row]; wih0 = Wih0[row]; }
    else if (grp == 1) bias = bih1[row] + bhh1[row];
    else { bias = bih2[row] + bhh2[row]; if (qt == 0) wlin_u = Wlin[u]; }
    const float blin_v = blin[0];

    const int la = (grp == 2) ? 1 : 0;     // A-matvec h source layer
    const int lb = grp;                    // B-matvec h source layer (own)
    // Precomputed LDS pointers (literal rd indexes these -> imm offsets only)
    const uint4* pA[2] = { &hbf[0][la][2 * qt], &hbf[1][la][2 * qt] };
    const uint4* pB[2] = { &hbf[0][lb][2 * qt], &hbf[1][lb][2 * qt] };
    _Float16* pW[2] = { (_Float16*)&hbf[0][grp][0] + u, (_Float16*)&hbf[1][grp][0] + u };

    const bool b0c = qt & 1, b1c = (qt >> 1) & 1;
    const float s1 = (qt == 2) ? 2.f : 1.f;   // tanh = 2*sigm(2x)-1 for gate g
    const float o1 = (qt == 2) ? 1.f : 0.f;
    float cc = 0.f;                        // cell state (leaders qt==0)

    __syncthreads();

    auto tick = [&](int T, int rd) {
        const int wr = rd ^ 1;
        float p0, p1, p2, p3;

        const uint4 a0 = pA[rd][0], a1 = pA[rd][1];
        p0 = dotseg(wA0, a0, a1, 0.f);
        p1 = dotseg(wA1, a0, a1, 0.f);
        p2 = dotseg(wA2, a0, a1, 0.f);
        p3 = dotseg(wA3, a0, a1, 0.f);
        if (grp != 0) {
            const uint4 c0 = pB[rd][0], c1 = pB[rd][1];
            p0 = dotseg(wB0, c0, c1, p0);
            p1 = dotseg(wB1, c0, c1, p1);
            p2 = dotseg(wB2, c0, c1, p2);
            p3 = dotseg(wB3, c0, c1, p3);
        }

        // quad transpose-reduce (DPP): lane qt ends with full sum of gate qt
        float k0 = (b0c ? p1 : p0) + fdpp<DPP_XOR1>(b0c ? p0 : p1);
        float k1 = (b0c ? p3 : p2) + fdpp<DPP_XOR1>(b0c ? p2 : p3);
        float g  = (b1c ? k1 : k0) + fdpp<DPP_XOR2>(b1c ? k0 : k1);
        g += bias;
        if (grp == 0) g += wih0 * xrow[(T < SQ) ? T : 0];

        // activation + quad combine (DPP)
        float t = 1.f / (1.f + __expf(-s1 * g));
        const float act = s1 * t - o1;     // sigm for i,f,o; tanh for g
        const float v1 = fdpp<DPP_XOR1>(act);
        const float v2 = fdpp<DPP_XOR2>(act);
        const float v3 = fdpp<DPP_XOR3>(act);

        const int step = T - grp;
        float yv = 0.f;
        if (qt == 0 && step >= 0 && step < SQ) {
            cc = v1 * cc + act * v2;       // sigm(f)*c + sigm(i)*tanh(g)
            float tc = fminf(fmaxf(cc, -15.f), 15.f);
            float e  = __expf(-2.f * tc);
            float h  = v3 * ((1.f - e) / (1.f + e));   // sigm(o)*tanh(c)
            *pW[wr] = (_Float16)h;
            if (grp == 2) yv = wlin_u * h;
            if (step == SQ - 1) {
                out[NB * SQ + grp * NB * HH + b * HH + u] = h;
                out[NB * SQ + 3 * NB * HH + grp * NB * HH + b * HH + u] = cc;
            }
        }
        if (grp == 2) {
            // head partials: quad + row sums (all DPP), 16 slots per buffer
            yv += fdpp<DPP_XOR1>(yv);
            yv += fdpp<DPP_XOR2>(yv);
            yv += fdpp<DPP_ROR4>(yv);
            yv += fdpp<DPP_ROR8>(yv);
            if ((k & 15) == 0) ybuf[rd][k >> 4] = yv;
        }
        if (grp == 0 && u == HH - 1) {
            // final head sum for step T-3 (u==63 quad of grp0 wave 3)
            const int sy = T - 3;
            if (sy >= 0 && sy < SQ) {
                const float4 v = ((const float4*)ybuf[rd ^ 1])[qt];
                float s = (v.x + v.y) + (v.z + v.w);
                s += fdpp<DPP_XOR1>(s);
                s += fdpp<DPP_XOR2>(s);
                if (qt == 3) out[b * SQ + sy] = s + blin_v;
            }
        }
        __syncthreads();
    };

    for (int T = 0; T < SQ + 4; T += 2) {  // ticks 0..4099 (needs 0..4098)
        tick(T, 0);
        tick(T + 1, 1);
    }
}

extern "C" void kernel_launch(void* const* d_in, const int* in_sizes, int n_in,
                              void* d_out, int out_size, void* d_ws, size_t ws_size,
                              hipStream_t stream) {
    const float* x    = (const float*)d_in[0];
    const float* Wih0 = (const float*)d_in[1];
    const float* Whh0 = (const float*)d_in[2];
    const float* bih0 = (const float*)d_in[3];
    const float* bhh0 = (const float*)d_in[4];
    const float* Wih1 = (const float*)d_in[5];
    const float* Whh1 = (const float*)d_in[6];
    const float* bih1 = (const float*)d_in[7];
    const float* bhh1 = (const float*)d_in[8];
    const float* Wih2 = (const float*)d_in[9];
    const float* Whh2 = (const float*)d_in[10];
    const float* bih2 = (const float*)d_in[11];
    const float* bhh2 = (const float*)d_in[12];
    const float* Wlin = (const float*)d_in[13];
    const float* blin = (const float*)d_in[14];
    float* out = (float*)d_out;

    lstm3_fused<<<NB, 768, 0, stream>>>(x, Wih0, Whh0, bih0, bhh0,
                                        Wih1, Whh1, bih1, bhh1,
                                        Wih2, Whh2, bih2, bhh2,
                                        Wlin, blin, out);
}

// Round 7
// 3395.628 us; speedup vs baseline: 9.4537x; 1.0062x over previous
//
#include <hip/hip_runtime.h>
#include <stdint.h>

// 3-layer LSTM (H=64, B=256, S=4096, DIN=1) + linear head.
// One block/batch element; 768 thr = 3 groups of 256 (group = layer), skewed
// pipeline (tick T: l0@T, l1@T-1, l2@T-2, y@T-3). Col-split matvec: thread
// (u,qt) does all 4 gate rows of unit u over col quarter qt (2 ds_read_b128).
// Pure-32-bit codegen: weights = packed fp16 pairs in u32 SSA vectors, h read
// as uint4, bit_cast at fdot2 -> dotseg = exactly 8 v_dot2_f32_f16.
// R7: VGPR=60 in R6 proved the compiler rematerialized weight load+cvt+pack
// in-loop (~190 extra VALU/tick/wave) chasing unreachable occupancy (grid is
// 1 block/CU). Fix: amdgpu_waves_per_eu(1,3) sets the real occupancy target,
// and an opaque asm pin makes weight regs non-rematerializable.

#define SQ 4096
#define HH 64
#define NB 256

typedef _Float16 h2  __attribute__((ext_vector_type(2)));
typedef uint32_t uv8 __attribute__((ext_vector_type(8)));

__device__ __forceinline__ h2 bch2(uint32_t u) { return __builtin_bit_cast(h2, u); }

template<int CTRL>
__device__ __forceinline__ float fdpp(float v) {
    return __builtin_bit_cast(float,
        __builtin_amdgcn_mov_dpp(__builtin_bit_cast(int, v), CTRL, 0xF, 0xF, true));
}
// quad_perm encodings: xor1=(1,0,3,2), xor2=(2,3,0,1), xor3=(3,2,1,0)
#define DPP_XOR1 0xB1
#define DPP_XOR2 0x4E
#define DPP_XOR3 0x1B
#define DPP_ROR4 0x124
#define DPP_ROR8 0x128

__device__ __forceinline__ uv8 load_seg(const float* __restrict__ p) {
    uv8 r;
#pragma unroll
    for (int j = 0; j < 8; ++j) {
        h2 t; t[0] = (_Float16)p[2 * j]; t[1] = (_Float16)p[2 * j + 1];
        r[j] = __builtin_bit_cast(uint32_t, t);
    }
    return r;
}

// Opaque pin: asm results cannot be rematerialized -> forces VGPR residency.
__device__ __forceinline__ void pin(uv8& r) {
#pragma unroll
    for (int j = 0; j < 8; ++j) {
        uint32_t t = r[j];
        asm volatile("" : "+v"(t));
        r[j] = t;
    }
}

// 16 fp16 weights (8 packed u32) . 16 fp16 h (two uint4) -> fp32 acc
__device__ __forceinline__ float dotseg(uv8 w, uint4 a, uint4 b, float acc) {
    acc = __builtin_amdgcn_fdot2(bch2(w[0]), bch2(a.x), acc, false);
    acc = __builtin_amdgcn_fdot2(bch2(w[1]), bch2(a.y), acc, false);
    acc = __builtin_amdgcn_fdot2(bch2(w[2]), bch2(a.z), acc, false);
    acc = __builtin_amdgcn_fdot2(bch2(w[3]), bch2(a.w), acc, false);
    acc = __builtin_amdgcn_fdot2(bch2(w[4]), bch2(b.x), acc, false);
    acc = __builtin_amdgcn_fdot2(bch2(w[5]), bch2(b.y), acc, false);
    acc = __builtin_amdgcn_fdot2(bch2(w[6]), bch2(b.z), acc, false);
    acc = __builtin_amdgcn_fdot2(bch2(w[7]), bch2(b.w), acc, false);
    return acc;
}

__global__ __launch_bounds__(768)
__attribute__((amdgpu_waves_per_eu(1, 3)))
void lstm3_fused(
    const float* __restrict__ x,
    const float* __restrict__ Wih0, const float* __restrict__ Whh0,
    const float* __restrict__ bih0, const float* __restrict__ bhh0,
    const float* __restrict__ Wih1, const float* __restrict__ Whh1,
    const float* __restrict__ bih1, const float* __restrict__ bhh1,
    const float* __restrict__ Wih2, const float* __restrict__ Whh2,
    const float* __restrict__ bih2, const float* __restrict__ bhh2,
    const float* __restrict__ Wlin, const float* __restrict__ blin,
    float* __restrict__ out)
{
    const int b   = blockIdx.x;
    const int tid = threadIdx.x;
    const int grp = tid >> 8;          // layer 0,1,2
    const int k   = tid & 255;
    const int u   = k >> 2;            // hidden unit
    const int qt  = k & 3;             // col quarter AND final gate index
    const int row = qt * HH + u;       // this thread's final gate row

    __shared__ __align__(16) float xrow[SQ];
    __shared__ __align__(16) uint4 hbf[2][3][8];   // [buf][layer][8x uint4 = 64 fp16]
    __shared__ __align__(16) float ybuf[2][16];    // per-row head partials

    for (int i = tid; i < SQ; i += 768) xrow[i] = x[b * SQ + i];
    if (tid < 48) ((uint4*)hbf)[tid] = make_uint4(0, 0, 0, 0);
    if (tid < 32) ((float*)ybuf)[tid] = 0.f;

    // ---- weights: 4 gate-row segments per matvec, packed fp16 in u32 SSA ----
    const float* WA = (grp == 0) ? Whh0 : (grp == 1) ? Wih1 : Wih2;
    const float* WB = (grp == 2) ? Whh2 : Whh1;        // unused by grp0
    uv8 wA0 = load_seg(WA + (0 * HH + u) * HH + 16 * qt);
    uv8 wA1 = load_seg(WA + (1 * HH + u) * HH + 16 * qt);
    uv8 wA2 = load_seg(WA + (2 * HH + u) * HH + 16 * qt);
    uv8 wA3 = load_seg(WA + (3 * HH + u) * HH + 16 * qt);
    pin(wA0); pin(wA1); pin(wA2); pin(wA3);
    uv8 wB0 = {}, wB1 = {}, wB2 = {}, wB3 = {};
    if (grp != 0) {
        wB0 = load_seg(WB + (0 * HH + u) * HH + 16 * qt);
        wB1 = load_seg(WB + (1 * HH + u) * HH + 16 * qt);
        wB2 = load_seg(WB + (2 * HH + u) * HH + 16 * qt);
        wB3 = load_seg(WB + (3 * HH + u) * HH + 16 * qt);
        pin(wB0); pin(wB1); pin(wB2); pin(wB3);
    }

    float bias = 0.f, wih0 = 0.f, wlin_u = 0.f;
    if (grp == 0) { bias = bih0[row] + bhh0[row]; wih0 = Wih0[row]; }
    else if (grp == 1) bias = bih1[row] + bhh1[row];
    else { bias = bih2[row] + bhh2[row]; if (qt == 0) wlin_u = Wlin[u]; }
    const float blin_v = blin[0];

    const int la = (grp == 2) ? 1 : 0;     // A-matvec h source layer
    const int lb = grp;                    // B-matvec h source layer (own)
    // Precomputed LDS pointers (literal rd indexes these -> imm offsets only)
    const uint4* pA[2] = { &hbf[0][la][2 * qt], &hbf[1][la][2 * qt] };
    const uint4* pB[2] = { &hbf[0][lb][2 * qt], &hbf[1][lb][2 * qt] };
    _Float16* pW[2] = { (_Float16*)&hbf[0][grp][0] + u, (_Float16*)&hbf[1][grp][0] + u };

    const bool b0c = qt & 1, b1c = (qt >> 1) & 1;
    const float s1 = (qt == 2) ? 2.f : 1.f;   // tanh = 2*sigm(2x)-1 for gate g
    const float o1 = (qt == 2) ? 1.f : 0.f;
    float cc = 0.f;                        // cell state (leaders qt==0)

    __syncthreads();

    auto tick = [&](int T, int rd) {
        const int wr = rd ^ 1;
        float p0, p1, p2, p3;

        const uint4 a0 = pA[rd][0], a1 = pA[rd][1];
        p0 = dotseg(wA0, a0, a1, 0.f);
        p1 = dotseg(wA1, a0, a1, 0.f);
        p2 = dotseg(wA2, a0, a1, 0.f);
        p3 = dotseg(wA3, a0, a1, 0.f);
        if (grp != 0) {
            const uint4 c0 = pB[rd][0], c1 = pB[rd][1];
            p0 = dotseg(wB0, c0, c1, p0);
            p1 = dotseg(wB1, c0, c1, p1);
            p2 = dotseg(wB2, c0, c1, p2);
            p3 = dotseg(wB3, c0, c1, p3);
        }

        // quad transpose-reduce (DPP): lane qt ends with full sum of gate qt
        float k0 = (b0c ? p1 : p0) + fdpp<DPP_XOR1>(b0c ? p0 : p1);
        float k1 = (b0c ? p3 : p2) + fdpp<DPP_XOR1>(b0c ? p2 : p3);
        float g  = (b1c ? k1 : k0) + fdpp<DPP_XOR2>(b1c ? k0 : k1);
        g += bias;
        if (grp == 0) g += wih0 * xrow[(T < SQ) ? T : 0];

        // activation + quad combine (DPP)
        float t = 1.f / (1.f + __expf(-s1 * g));
        const float act = s1 * t - o1;     // sigm for i,f,o; tanh for g
        const float v1 = fdpp<DPP_XOR1>(act);
        const float v2 = fdpp<DPP_XOR2>(act);
        const float v3 = fdpp<DPP_XOR3>(act);

        const int step = T - grp;
        float yv = 0.f;
        if (qt == 0 && step >= 0 && step < SQ) {
            cc = v1 * cc + act * v2;       // sigm(f)*c + sigm(i)*tanh(g)
            float tc = fminf(fmaxf(cc, -15.f), 15.f);
            float e  = __expf(-2.f * tc);
            float h  = v3 * ((1.f - e) / (1.f + e));   // sigm(o)*tanh(c)
            *pW[wr] = (_Float16)h;
            if (grp == 2) yv = wlin_u * h;
            if (step == SQ - 1) {
                out[NB * SQ + grp * NB * HH + b * HH + u] = h;
                out[NB * SQ + 3 * NB * HH + grp * NB * HH + b * HH + u] = cc;
            }
        }
        if (grp == 2) {
            // head partials: quad + row sums (all DPP), 16 slots per buffer
            yv += fdpp<DPP_XOR1>(yv);
            yv += fdpp<DPP_XOR2>(yv);
            yv += fdpp<DPP_ROR4>(yv);
            yv += fdpp<DPP_ROR8>(yv);
            if ((k & 15) == 0) ybuf[rd][k >> 4] = yv;
        }
        if (grp == 0 && u == HH - 1) {
            // final head sum for step T-3 (u==63 quad of grp0 wave 3)
            const int sy = T - 3;
            if (sy >= 0 && sy < SQ) {
                const float4 v = ((const float4*)ybuf[rd ^ 1])[qt];
                float s = (v.x + v.y) + (v.z + v.w);
                s += fdpp<DPP_XOR1>(s);
                s += fdpp<DPP_XOR2>(s);
                if (qt == 3) out[b * SQ + sy] = s + blin_v;
            }
        }
        __syncthreads();
    };

    for (int T = 0; T < SQ + 4; T += 2) {  // ticks 0..4099 (needs 0..4098)
        tick(T, 0);
        tick(T + 1, 1);
    }
}

extern "C" void kernel_launch(void* const* d_in, const int* in_sizes, int n_in,
                              void* d_out, int out_size, void* d_ws, size_t ws_size,
                              hipStream_t stream) {
    const float* x    = (const float*)d_in[0];
    const float* Wih0 = (const float*)d_in[1];
    const float* Whh0 = (const float*)d_in[2];
    const float* bih0 = (const float*)d_in[3];
    const float* bhh0 = (const float*)d_in[4];
    const float* Wih1 = (const float*)d_in[5];
    const float* Whh1 = (const float*)d_in[6];
    const float* bih1 = (const float*)d_in[7];
    const float* bhh1 = (const float*)d_in[8];
    const float* Wih2 = (const float*)d_in[9];
    const float* Whh2 = (const float*)d_in[10];
    const float* bih2 = (const float*)d_in[11];
    const float* bhh2 = (const float*)d_in[12];
    const float* Wlin = (const float*)d_in[13];
    const float* blin = (const float*)d_in[14];
    float* out = (float*)d_out;

    lstm3_fused<<<NB, 768, 0, stream>>>(x, Wih0, Whh0, bih0, bhh0,
                                        Wih1, Whh1, bih1, bhh1,
                                        Wih2, Whh2, bih2, bhh2,
                                        Wlin, blin, out);
}